// Round 1
// baseline (319.727 us; speedup 1.0000x reference)
//
#include <hip/hip_runtime.h>
#include <hip/hip_fp16.h>

// adj[b] = tanh(relu(E_b @ E_b^T)) + 0.5*I
// E_b = concat(spatial[b] (2048x64), temporal[b] (64x64)) fp32 -> fp16 MFMA,
// fp32 accumulate. Output: [16, 2112, 2112] fp32.
// R7: drop the Ct LDS epilogue transpose entirely. The 16x16x32 C/D layout
// (col=lane&15, row=(lane>>4)*4+i) already yields 16-lane-contiguous 64 B
// segments on per-lane scalar stores, so we store straight from the
// accumulators with nontemporal global_store_dword (write-once output,
// keep it out of L2). LDS drops 45 KB -> 27.6 KB: 3 -> 4-5 WGs/CU.
// XCD-partitioned tile order kept from R5/R6 (validated win).

#define B_BATCH   16
#define N_SPATIAL 2048
#define T_TEMP    64
#define M_NODES   2112     // 33 * 64
#define D_FEAT    64
#define TILE      64
#define LDSK      72       // fp16 k-stride (+8 pad)

// per batch: 33 ti strips x 17 tj-groups (16 groups of 2 tiles + 1 of 1)
#define GROUPS_PER_STRIP 17
#define WGS_PER_BATCH    (33 * GROUPS_PER_STRIP)   // 561
#define TOTAL_WGS        (WGS_PER_BATCH * B_BATCH) // 8976 = 8 * 1122
#define WGS_PER_XCD      (TOTAL_WGS / 8)           // 1122 = 2 batches

typedef _Float16 f16x8 __attribute__((ext_vector_type(8)));
typedef float    f32x4 __attribute__((ext_vector_type(4)));

__device__ __forceinline__ f16x8 cvt2(const float4* p) {
    float4 a = p[0], c = p[1];
    f16x8 h;
    h[0] = (_Float16)a.x; h[1] = (_Float16)a.y;
    h[2] = (_Float16)a.z; h[3] = (_Float16)a.w;
    h[4] = (_Float16)c.x; h[5] = (_Float16)c.y;
    h[6] = (_Float16)c.z; h[7] = (_Float16)c.w;
    return h;
}

__global__ __launch_bounds__(256, 4)
void gram_tanh_mfma(const float* __restrict__ sp,
                    const float* __restrict__ tp,
                    float* __restrict__ out)
{
    // ---- XCD-aware decode: wg lin -> XCD (lin&7, round-robin dispatch);
    // XCD k owns local ids [0,1122) = batches 2k,2k+1, tj fastest.
    const int lin = blockIdx.x;
    const int xcd = lin & 7;
    const int l   = lin >> 3;            // 0..1121
    const int bo  = l / WGS_PER_BATCH;   // 0,1
    const int rr  = l - bo * WGS_PER_BATCH;
    const int ti  = rr / GROUPS_PER_STRIP;          // 0..32
    const int g   = rr - ti * GROUPS_PER_STRIP;     // 0..16
    const int b   = 2 * xcd + bo;
    const int tj0 = 2 * g;
    const bool have2 = (tj0 + 1 < 33);
    const int tj1 = have2 ? tj0 + 1 : 32;           // clamp (g==16 -> dup of tj0)

    __shared__ __align__(16) _Float16 As[TILE][LDSK];       //  9216 B
    __shared__ __align__(16) _Float16 Bs[2][TILE][LDSK];    // 18432 B -> 27648 B

    const int tid = threadIdx.x;

    // ---- stage + convert fp32 -> fp16: row = tid>>2, 16 consecutive k ----
    {
        const int row = tid >> 2;
        const int kb  = (tid & 3) * 16;
        const float* srcA = (ti < 32)
            ? sp + ((size_t)b * N_SPATIAL + (size_t)ti * TILE) * D_FEAT
            : tp + (size_t)b * T_TEMP * D_FEAT;
        const float* srcB0 = (tj0 < 32)
            ? sp + ((size_t)b * N_SPATIAL + (size_t)tj0 * TILE) * D_FEAT
            : tp + (size_t)b * T_TEMP * D_FEAT;
        const float* srcB1 = (tj1 < 32)
            ? sp + ((size_t)b * N_SPATIAL + (size_t)tj1 * TILE) * D_FEAT
            : tp + (size_t)b * T_TEMP * D_FEAT;
        const float4* pa  = (const float4*)(srcA  + (size_t)row * D_FEAT + kb);
        const float4* pb0 = (const float4*)(srcB0 + (size_t)row * D_FEAT + kb);
        const float4* pb1 = (const float4*)(srcB1 + (size_t)row * D_FEAT + kb);

        *(f16x8*)&As[row][kb]        = cvt2(pa);
        *(f16x8*)&As[row][kb + 8]    = cvt2(pa + 2);
        *(f16x8*)&Bs[0][row][kb]     = cvt2(pb0);
        *(f16x8*)&Bs[0][row][kb + 8] = cvt2(pb0 + 2);
        *(f16x8*)&Bs[1][row][kb]     = cvt2(pb1);
        *(f16x8*)&Bs[1][row][kb + 8] = cvt2(pb1 + 2);
    }
    __syncthreads();   // the ONLY barrier

    // ---- MFMA: wave w -> rows [16w,16w+16) x 2 sub-tiles of 64 cols ----
    const int wave = tid >> 6;
    const int lane = tid & 63;
    const int lr   = lane & 15;   // m (A) / n (B) within 16-tile = out col
    const int q    = lane >> 4;   // quad -> k-slice / C row group

    f32x4 acc[2][4];
    #pragma unroll
    for (int n = 0; n < 2; ++n)
        #pragma unroll
        for (int tt = 0; tt < 4; ++tt) acc[n][tt] = (f32x4){0.f, 0.f, 0.f, 0.f};

    #pragma unroll
    for (int s = 0; s < 2; ++s) {                 // K = 64 = 2 x 32
        f16x8 afrag = *(const f16x8*)&As[wave * 16 + lr][s * 32 + q * 8];
        #pragma unroll
        for (int n = 0; n < 2; ++n) {
            #pragma unroll
            for (int tt = 0; tt < 4; ++tt) {
                f16x8 bfrag = *(const f16x8*)&Bs[n][tt * 16 + lr][s * 32 + q * 8];
                acc[n][tt] = __builtin_amdgcn_mfma_f32_16x16x32_f16(afrag, bfrag, acc[n][tt], 0, 0, 0);
            }
        }
    }

    // ---- epilogue: tanh(relu)+diag, store DIRECT from acc registers ----
    // C/D layout per 16x16 tile: col = lane&15, row = (lane>>4)*4 + i.
    // A wave's store_dword covers 4 rows x 16 consecutive lanes = 4 aligned
    // 64 B segments -> full HBM write efficiency, no LDS round-trip.
    #pragma unroll
    for (int n = 0; n < 2; ++n) {
        if (n == 1 && !have2) break;              // wave-uniform skip (dup tile)
        const int tjn = n ? tj1 : tj0;
        const bool diagT = (ti == tjn);
        // base: row (wave*16 + q*4), col (tjn*64 + lr)
        float* dst0 = out + (size_t)b * M_NODES * M_NODES
                          + (size_t)(ti * TILE + wave * 16 + q * 4) * M_NODES
                          + (size_t)(tjn * TILE + lr);
        #pragma unroll
        for (int tt = 0; tt < 4; ++tt) {
            const int col = tt * 16 + lr;         // col within 64-wide tile
            #pragma unroll
            for (int i = 0; i < 4; ++i) {
                const int row = wave * 16 + q * 4 + i;  // row within 64-tall tile
                float x = fmaxf(acc[n][tt][i], 0.f);
                // tanh(x), x>=0: 1 - 2/(e^{2x}+1); exp->inf saturates to 1
                float e = __expf(2.f * x);
                float v = 1.f - 2.f * __builtin_amdgcn_rcpf(e + 1.f);
                if (diagT && (row == col)) v += 0.5f;
                __builtin_nontemporal_store(v, dst0 + (size_t)i * M_NODES + tt * 16);
            }
        }
    }
}

extern "C" void kernel_launch(void* const* d_in, const int* in_sizes, int n_in,
                              void* d_out, int out_size, void* d_ws, size_t ws_size,
                              hipStream_t stream) {
    const float* sp = (const float*)d_in[0];   // [16, 2048, 64] fp32
    const float* tp = (const float*)d_in[1];   // [16, 64, 64]   fp32
    float* out = (float*)d_out;                // [16, 2112, 2112] fp32

    dim3 grid(TOTAL_WGS);                      // 8976; kernel does XCD decode
    dim3 block(256);
    hipLaunchKernelGGL(gram_tanh_mfma, grid, block, 0, stream, sp, tp, out);
}

// Round 3
// 290.608 us; speedup vs baseline: 1.1002x; 1.1002x over previous
//
#include <hip/hip_runtime.h>
#include <hip/hip_fp16.h>

// adj[b] = tanh(relu(E_b @ E_b^T)) + 0.5*I
// E_b = concat(spatial[b] (2048x64), temporal[b] (64x64)) fp32 -> fp16 MFMA,
// fp32 accumulate. Output: [16, 2112, 2112] fp32.
// R9 = R8 resubmit (R8 bench was an infra failure: "container failed twice",
// no signal). Swapped-operand MFMA epilogue: mfma(bfrag, afrag) computes C^T,
// whose C/D layout (col=lane&15, row=(lane>>4)*4+i) gives each lane 4
// CONSECUTIVE output columns of one output row -> direct float4 stores from
// the accumulator. No Ct LDS transpose (R6), no scalar/nontemporal stores
// (R7 regression: 4x store instrs + nt defeats L2 write-combining).
// Each store instr: 16 rows x 64 B = 1 KB, fully coalesced.
// LDS 27.6 KB -> 4+ WGs/CU. XCD-partitioned tile order kept (R5 win).

#define B_BATCH   16
#define N_SPATIAL 2048
#define T_TEMP    64
#define M_NODES   2112     // 33 * 64
#define D_FEAT    64
#define TILE      64
#define LDSK      72       // fp16 k-stride (+8 pad)

// per batch: 33 ti strips x 17 tj-groups (16 groups of 2 tiles + 1 of 1)
#define GROUPS_PER_STRIP 17
#define WGS_PER_BATCH    (33 * GROUPS_PER_STRIP)   // 561
#define TOTAL_WGS        (WGS_PER_BATCH * B_BATCH) // 8976 = 8 * 1122
#define WGS_PER_XCD      (TOTAL_WGS / 8)           // 1122 = 2 batches

typedef _Float16 f16x8 __attribute__((ext_vector_type(8)));
typedef float    f32x4 __attribute__((ext_vector_type(4)));

__device__ __forceinline__ f16x8 cvt2(const float4* p) {
    float4 a = p[0], c = p[1];
    f16x8 h;
    h[0] = (_Float16)a.x; h[1] = (_Float16)a.y;
    h[2] = (_Float16)a.z; h[3] = (_Float16)a.w;
    h[4] = (_Float16)c.x; h[5] = (_Float16)c.y;
    h[6] = (_Float16)c.z; h[7] = (_Float16)c.w;
    return h;
}

__global__ __launch_bounds__(256, 4)
void gram_tanh_mfma(const float* __restrict__ sp,
                    const float* __restrict__ tp,
                    float* __restrict__ out)
{
    // ---- XCD-aware decode: wg lin -> XCD (lin&7, round-robin dispatch);
    // XCD k owns local ids [0,1122) = batches 2k,2k+1, tj fastest.
    const int lin = blockIdx.x;
    const int xcd = lin & 7;
    const int l   = lin >> 3;            // 0..1121
    const int bo  = l / WGS_PER_BATCH;   // 0,1
    const int rr  = l - bo * WGS_PER_BATCH;
    const int ti  = rr / GROUPS_PER_STRIP;          // 0..32
    const int g   = rr - ti * GROUPS_PER_STRIP;     // 0..16
    const int b   = 2 * xcd + bo;
    const int tj0 = 2 * g;
    const bool have2 = (tj0 + 1 < 33);
    const int tj1 = have2 ? tj0 + 1 : 32;           // clamp (g==16 -> dup of tj0)

    __shared__ __align__(16) _Float16 As[TILE][LDSK];       //  9216 B
    __shared__ __align__(16) _Float16 Bs[2][TILE][LDSK];    // 18432 B -> 27648 B

    const int tid = threadIdx.x;

    // ---- stage + convert fp32 -> fp16: row = tid>>2, 16 consecutive k ----
    {
        const int row = tid >> 2;
        const int kb  = (tid & 3) * 16;
        const float* srcA = (ti < 32)
            ? sp + ((size_t)b * N_SPATIAL + (size_t)ti * TILE) * D_FEAT
            : tp + (size_t)b * T_TEMP * D_FEAT;
        const float* srcB0 = (tj0 < 32)
            ? sp + ((size_t)b * N_SPATIAL + (size_t)tj0 * TILE) * D_FEAT
            : tp + (size_t)b * T_TEMP * D_FEAT;
        const float* srcB1 = (tj1 < 32)
            ? sp + ((size_t)b * N_SPATIAL + (size_t)tj1 * TILE) * D_FEAT
            : tp + (size_t)b * T_TEMP * D_FEAT;
        const float4* pa  = (const float4*)(srcA  + (size_t)row * D_FEAT + kb);
        const float4* pb0 = (const float4*)(srcB0 + (size_t)row * D_FEAT + kb);
        const float4* pb1 = (const float4*)(srcB1 + (size_t)row * D_FEAT + kb);

        *(f16x8*)&As[row][kb]        = cvt2(pa);
        *(f16x8*)&As[row][kb + 8]    = cvt2(pa + 2);
        *(f16x8*)&Bs[0][row][kb]     = cvt2(pb0);
        *(f16x8*)&Bs[0][row][kb + 8] = cvt2(pb0 + 2);
        *(f16x8*)&Bs[1][row][kb]     = cvt2(pb1);
        *(f16x8*)&Bs[1][row][kb + 8] = cvt2(pb1 + 2);
    }
    __syncthreads();   // the ONLY barrier

    // ---- MFMA (swapped operands -> transposed C/D layout) ----
    // acc[n][tt] = C^T tile: D'[m''=Bs-row][n''=As-row].
    // Layout: lane&15 = n'' = OUTPUT ROW within wave's 16-row slice;
    //         (lane>>4)*4+i = m'' = OUTPUT COL within tt's 16-col block.
    const int wave = tid >> 6;
    const int lane = tid & 63;
    const int lr   = lane & 15;   // output row within 16-slice
    const int q    = lane >> 4;   // output col quad -> cols q*4..q*4+3

    f32x4 acc[2][4];
    #pragma unroll
    for (int n = 0; n < 2; ++n)
        #pragma unroll
        for (int tt = 0; tt < 4; ++tt) acc[n][tt] = (f32x4){0.f, 0.f, 0.f, 0.f};

    #pragma unroll
    for (int s = 0; s < 2; ++s) {                 // K = 64 = 2 x 32
        f16x8 afrag = *(const f16x8*)&As[wave * 16 + lr][s * 32 + q * 8];
        #pragma unroll
        for (int n = 0; n < 2; ++n) {
            #pragma unroll
            for (int tt = 0; tt < 4; ++tt) {
                f16x8 bfrag = *(const f16x8*)&Bs[n][tt * 16 + lr][s * 32 + q * 8];
                // SWAPPED: bfrag in A-slot, afrag in B-slot -> C^T layout
                acc[n][tt] = __builtin_amdgcn_mfma_f32_16x16x32_f16(bfrag, afrag, acc[n][tt], 0, 0, 0);
            }
        }
    }

    // ---- epilogue: tanh(relu)+diag, float4 store DIRECT from acc ----
    // Per store instr: lanes with same lr share a row; q spans 4 adjacent
    // float4s -> 16 rows x 64 B contiguous = 1 KB, fully coalesced.
    #pragma unroll
    for (int n = 0; n < 2; ++n) {
        if (n == 1 && !have2) break;              // wave-uniform skip (dup tile)
        const int tjn = n ? tj1 : tj0;
        const bool diagT = (ti == tjn);
        const int r_loc = wave * 16 + lr;         // row within 64-tall tile
        float* dst = out + (size_t)b * M_NODES * M_NODES
                         + (size_t)(ti * TILE + r_loc) * M_NODES
                         + (size_t)(tjn * TILE + q * 4);
        #pragma unroll
        for (int tt = 0; tt < 4; ++tt) {
            const int c_loc = tt * 16 + q * 4;    // col base within 64-wide tile
            float4 o;
            float* po = &o.x;
            #pragma unroll
            for (int i = 0; i < 4; ++i) {
                float x = fmaxf(acc[n][tt][i], 0.f);
                // tanh(x), x>=0: 1 - 2/(e^{2x}+1); exp->inf saturates to 1
                float e = __expf(2.f * x);
                float v = 1.f - 2.f * __builtin_amdgcn_rcpf(e + 1.f);
                if (diagT && (r_loc == c_loc + i)) v += 0.5f;
                po[i] = v;
            }
            *(float4*)(dst + tt * 16) = o;
        }
    }
}

extern "C" void kernel_launch(void* const* d_in, const int* in_sizes, int n_in,
                              void* d_out, int out_size, void* d_ws, size_t ws_size,
                              hipStream_t stream) {
    const float* sp = (const float*)d_in[0];   // [16, 2048, 64] fp32
    const float* tp = (const float*)d_in[1];   // [16, 64, 64]   fp32
    float* out = (float*)d_out;                // [16, 2112, 2112] fp32

    dim3 grid(TOTAL_WGS);                      // 8976; kernel does XCD decode
    dim3 block(256);
    hipLaunchKernelGGL(gram_tanh_mfma, grid, block, 0, stream, sp, tp, out);
}